// Round 1
// baseline (1751.055 us; speedup 1.0000x reference)
//
#include <hip/hip_runtime.h>
#include <math.h>

#define SEQ  2048
#define BATCH 128
#define NINP   64
#define NHID  128
#define NOUT   10

// ---------------------------------------------------------------------------
// K1: xW[s][b][j] = sum_i x[s][b][i]*Wxh[i][j] + bh[j]
// 32 rows per block, 256 threads, thread tile = 4 rows x 4 cols.
// Writes into the h-region of d_out (scan will overwrite in place).
// ---------------------------------------------------------------------------
__global__ __launch_bounds__(256) void proj_kernel(const float* __restrict__ x,
                                                   const float* __restrict__ Wxh,
                                                   const float* __restrict__ bh,
                                                   float* __restrict__ xw) {
    __shared__ float Wlds[NINP * NHID];   // 32 KB
    __shared__ float xs[32 * NINP];       // 8 KB
    const int t = threadIdx.x;
    const size_t r0 = (size_t)blockIdx.x * 32;

    // stage Wxh (8192 floats) and the 32-row x tile (2048 floats)
#pragma unroll
    for (int i = 0; i < 8; ++i)
        ((float4*)Wlds)[t + 256 * i] = ((const float4*)Wxh)[t + 256 * i];
    const float4* xg = (const float4*)(x + r0 * NINP);
    ((float4*)xs)[t]       = xg[t];
    ((float4*)xs)[t + 256] = xg[t + 256];
    __syncthreads();

    const int tj = t & 31;        // 32 column groups
    const int tr = t >> 5;        // 8 row groups
    const int j  = 4 * tj;
    const float4 bhv = *(const float4*)(bh + j);
    float acc[4][4];
#pragma unroll
    for (int r = 0; r < 4; ++r) {
        acc[r][0] = bhv.x; acc[r][1] = bhv.y; acc[r][2] = bhv.z; acc[r][3] = bhv.w;
    }
#pragma unroll 8
    for (int i = 0; i < NINP; ++i) {
        const float4 w4 = *(const float4*)&Wlds[i * NHID + j];
#pragma unroll
        for (int r = 0; r < 4; ++r) {
            const float xv = xs[(4 * tr + r) * NINP + i];  // 2-addr broadcast, free
            acc[r][0] = fmaf(xv, w4.x, acc[r][0]);
            acc[r][1] = fmaf(xv, w4.y, acc[r][1]);
            acc[r][2] = fmaf(xv, w4.z, acc[r][2]);
            acc[r][3] = fmaf(xv, w4.w, acc[r][3]);
        }
    }
#pragma unroll
    for (int r = 0; r < 4; ++r) {
        float4 o = { acc[r][0], acc[r][1], acc[r][2], acc[r][3] };
        *(float4*)(xw + (r0 + 4 * tr + r) * NHID + j) = o;
    }
}

// ---------------------------------------------------------------------------
// K2: sequential scan, one block per batch row (128 blocks, no cross-WG sync).
// 256 threads = 4 waves; j = 32*wave + (lane&31), half = lane>>5 (k-split).
// Whh column slice in 64 VGPRs; h_prev double-buffered in LDS (1 barrier/step);
// split-k partner is lane^32 (same wave) -> single shfl_xor reduce.
// hbuf initially holds xW; h[t] overwrites xw[t] in place.
// ---------------------------------------------------------------------------
__global__ __launch_bounds__(256) void scan_kernel(const float* __restrict__ Whh,
                                                   float* __restrict__ hbuf) {
    const int b = blockIdx.x;
    const int t = threadIdx.x;
    const int w = t >> 6;
    const int l = t & 63;
    const int j = 32 * w + (l & 31);
    const int half = l >> 5;

    // preload Whh[64*half + kk][j], kk = 0..63 into registers
    float wreg[64];
    const float* wp = Whh + (size_t)(64 * half) * NHID + j;
#pragma unroll
    for (int kk = 0; kk < 64; ++kk) wreg[kk] = wp[(size_t)kk * NHID];

    __shared__ float hs[2][NHID];
    if (t < 2 * NHID) ((float*)hs)[t] = 0.f;   // h_{-1} = 0

    const bool writer = (l < 32);
    float* rowbase = hbuf + (size_t)b * NHID;

    // prefetch xw for t = 0,1,2 (writer lanes only)
    float xw0 = writer ? rowbase[(size_t)0 * BATCH * NHID + j] : 0.f;
    float xw1 = writer ? rowbase[(size_t)1 * BATCH * NHID + j] : 0.f;
    float xw2 = writer ? rowbase[(size_t)2 * BATCH * NHID + j] : 0.f;
    __syncthreads();

    for (int ts = 0; ts < SEQ; ++ts) {
        const float* hp = &hs[ts & 1][64 * half];
        float a0 = 0.f, a1 = 0.f, a2 = 0.f, a3 = 0.f;
#pragma unroll
        for (int q = 0; q < 16; ++q) {
            const float4 h4 = *(const float4*)(hp + 4 * q);  // wave-broadcast read
            a0 = fmaf(h4.x, wreg[4 * q + 0], a0);
            a1 = fmaf(h4.y, wreg[4 * q + 1], a1);
            a2 = fmaf(h4.z, wreg[4 * q + 2], a2);
            a3 = fmaf(h4.w, wreg[4 * q + 3], a3);
        }
        float acc = (a0 + a1) + (a2 + a3);
        acc += __shfl_xor(acc, 32, 64);           // combine k-halves (same wave)
        const float hv = tanhf(acc + xw0);

        // rotate prefetch queue (xw[t+3] read before h[t+3] ever written)
        xw0 = xw1; xw1 = xw2;
        if (ts + 3 < SEQ)
            xw2 = writer ? rowbase[(size_t)(ts + 3) * BATCH * NHID + j] : 0.f;

        if (writer) {
            hs[(ts & 1) ^ 1][j] = hv;                        // next step's h_prev
            rowbase[(size_t)ts * BATCH * NHID + j] = hv;     // h output (in place)
        }
        __syncthreads();   // single barrier per step (double-buffered hs)
    }
}

// ---------------------------------------------------------------------------
// K3: logits = h_last @ Why + by   (tiny: 1280 outputs)
// ---------------------------------------------------------------------------
__global__ __launch_bounds__(256) void head_kernel(const float* __restrict__ hlast,
                                                   const float* __restrict__ Why,
                                                   const float* __restrict__ by,
                                                   float* __restrict__ out) {
    const int idx = blockIdx.x * 256 + threadIdx.x;
    if (idx >= BATCH * NOUT) return;
    const int b = idx / NOUT;
    const int o = idx % NOUT;
    const float* h = hlast + (size_t)b * NHID;
    float acc = by[o];
#pragma unroll 8
    for (int k = 0; k < NHID; ++k)
        acc = fmaf(h[k], Why[(size_t)k * NOUT + o], acc);
    out[idx] = acc;
}

// ---------------------------------------------------------------------------
extern "C" void kernel_launch(void* const* d_in, const int* in_sizes, int n_in,
                              void* d_out, int out_size, void* d_ws, size_t ws_size,
                              hipStream_t stream) {
    const float* x   = (const float*)d_in[0];
    const float* Wxh = (const float*)d_in[1];
    const float* Whh = (const float*)d_in[2];
    const float* Why = (const float*)d_in[3];
    const float* bh  = (const float*)d_in[4];
    const float* by  = (const float*)d_in[5];
    float* out  = (float*)d_out;
    float* hreg = out + BATCH * NOUT;   // h region starts after the 1280 logits

    proj_kernel<<<(SEQ * BATCH) / 32, 256, 0, stream>>>(x, Wxh, bh, hreg);
    scan_kernel<<<BATCH, 256, 0, stream>>>(Whh, hreg);
    head_kernel<<<5, 256, 0, stream>>>(hreg + (size_t)(SEQ - 1) * BATCH * NHID,
                                       Why, by, out);
}

// Round 3
// 1229.621 us; speedup vs baseline: 1.4241x; 1.4241x over previous
//
#include <hip/hip_runtime.h>
#include <math.h>

#define SEQ   2048
#define BATCH  128
#define NINP    64
#define NHID   128
#define NOUT    10
#define CH      64              // timesteps per LDS chunk
#define NCHUNK (SEQ / CH)

typedef const float __attribute__((address_space(1)))* gptr_t;
typedef float       __attribute__((address_space(3)))* lptr_t;

// ---------------------------------------------------------------------------
// K1: xW[s][b][j] = sum_i x[s][b][i]*Wxh[i][j] + bh[j]
// 32 rows per block, 256 threads, thread tile = 4 rows x 4 cols.
// Writes into the h-region of d_out (scan overwrites in place).
// ---------------------------------------------------------------------------
__global__ __launch_bounds__(256) void proj_kernel(const float* __restrict__ x,
                                                   const float* __restrict__ Wxh,
                                                   const float* __restrict__ bh,
                                                   float* __restrict__ xw) {
    __shared__ float Wlds[NINP * NHID];   // 32 KB
    __shared__ float xs[32 * NINP];       // 8 KB
    const int t = threadIdx.x;
    const size_t r0 = (size_t)blockIdx.x * 32;

#pragma unroll
    for (int i = 0; i < 8; ++i)
        ((float4*)Wlds)[t + 256 * i] = ((const float4*)Wxh)[t + 256 * i];
    const float4* xg = (const float4*)(x + r0 * NINP);
    ((float4*)xs)[t]       = xg[t];
    ((float4*)xs)[t + 256] = xg[t + 256];
    __syncthreads();

    const int tj = t & 31;
    const int tr = t >> 5;
    const int j  = 4 * tj;
    const float4 bhv = *(const float4*)(bh + j);
    float acc[4][4];
#pragma unroll
    for (int r = 0; r < 4; ++r) {
        acc[r][0] = bhv.x; acc[r][1] = bhv.y; acc[r][2] = bhv.z; acc[r][3] = bhv.w;
    }
#pragma unroll 8
    for (int i = 0; i < NINP; ++i) {
        const float4 w4 = *(const float4*)&Wlds[i * NHID + j];
#pragma unroll
        for (int r = 0; r < 4; ++r) {
            const float xv = xs[(4 * tr + r) * NINP + i];
            acc[r][0] = fmaf(xv, w4.x, acc[r][0]);
            acc[r][1] = fmaf(xv, w4.y, acc[r][1]);
            acc[r][2] = fmaf(xv, w4.z, acc[r][2]);
            acc[r][3] = fmaf(xv, w4.w, acc[r][3]);
        }
    }
#pragma unroll
    for (int r = 0; r < 4; ++r) {
        float4 o = { acc[r][0], acc[r][1], acc[r][2], acc[r][3] };
        *(float4*)(xw + (r0 + 4 * tr + r) * NHID + j) = o;
    }
}

// ---------------------------------------------------------------------------
// K2: sequential scan, one block (4 waves) per batch row.
// j = 32*wave + (lane&31), half = lane>>5 (2-way k-split, partner = lane^32).
// Whh slice pinned in 64 VGPRs. h double-buffered in LDS.
// xw staged per 64-step chunk via async global_load_lds (double-buffered);
// steady loop uses RAW s_barrier + lgkmcnt(0) only -> chunk loads and h
// stores stay in flight across step barriers (no per-step vmcnt drain).
// ---------------------------------------------------------------------------
__global__ __launch_bounds__(256) void scan_kernel(const float* __restrict__ Whh,
                                                   float* __restrict__ hbuf) {
    __shared__ float xwc[2][CH][NHID];   // 64 KB, double-buffered xw chunks
    __shared__ float hs[2][NHID];        // 1 KB, double-buffered h state

    const int b = blockIdx.x;
    const int t = threadIdx.x;
    const int w = t >> 6;
    const int l = t & 63;
    const int j = 32 * w + (l & 31);
    const int half = l >> 5;
    const bool writer = (l < 32);

    // ---- Whh column slice -> 64 VGPRs, pinned against remat/spill ----
    float wreg[64];
    {
        const float* wp = Whh + (size_t)(64 * half) * NHID + j;
#pragma unroll
        for (int kk = 0; kk < 64; ++kk) wreg[kk] = wp[(size_t)kk * NHID];
#pragma unroll
        for (int kk = 0; kk < 64; ++kk) asm volatile("" : "+v"(wreg[kk]));
    }

    hs[0][t & 127] = 0.f;   // t covers 0..255 -> both buffers
    hs[1][t & 127] = 0.f;

    float* rowbase = hbuf + (size_t)b * NHID;

    // ---- async chunk loader: chunk c -> LDS buffer nb ----
    // per wave: 8 instrs x (64 lanes x 16B) = 8 KB; 4 waves cover 32 KB chunk
    auto issue_chunk = [&](int c, int nb) {
#pragma unroll
        for (int i = 0; i < 8; ++i) {
            const int f  = (i * 4 + w) * 256 + l * 4;  // float offset in chunk
            const int tl = f >> 7;                     // local timestep
            const int jj = f & 127;                    // hidden index
            const float* gp = hbuf + ((size_t)(c * CH + tl) * BATCH + b) * NHID + jj;
            lptr_t lp = (lptr_t)&xwc[nb][0][0] + (i * 4 + w) * 256;  // wave-uniform
            __builtin_amdgcn_global_load_lds((gptr_t)gp, lp, 16, 0, 0);
        }
    };

    issue_chunk(0, 0);
    asm volatile("s_waitcnt vmcnt(0)" ::: "memory");
    __syncthreads();

    int cbuf = 0;
    for (int c = 0; c < NCHUNK; ++c) {
        if (c + 1 < NCHUNK) issue_chunk(c + 1, cbuf ^ 1);
        const float (*xwcur)[NHID] = xwc[cbuf];

        for (int ts = 0; ts < CH; ++ts) {
            const float* hp = &hs[ts & 1][64 * half];
            float a0 = 0.f, a1 = 0.f, a2 = 0.f, a3 = 0.f;
#pragma unroll
            for (int q = 0; q < 16; ++q) {
                const float4 h4 = *(const float4*)(hp + 4 * q);  // 2-addr broadcast
                a0 = fmaf(h4.x, wreg[4 * q + 0], a0);
                a1 = fmaf(h4.y, wreg[4 * q + 1], a1);
                a2 = fmaf(h4.z, wreg[4 * q + 2], a2);
                a3 = fmaf(h4.w, wreg[4 * q + 3], a3);
            }
            float acc = (a0 + a1) + (a2 + a3);
            acc += __shfl_xor(acc, 32, 64);      // combine k-halves (same wave)

            if (writer) {
                const float z  = acc + xwcur[ts][j];
                // fast tanh: (e-1)/(e+1), e = 2^(z*2*log2e), clamped (sat region)
                const float zc = fminf(fmaxf(z, -15.f), 15.f);
                const float e  = __builtin_amdgcn_exp2f(zc * 2.8853900817779268f);
                const float hv = (e - 1.f) * __builtin_amdgcn_rcpf(e + 1.f);
                hs[(ts & 1) ^ 1][j] = hv;                              // next h_prev
                rowbase[(size_t)(c * CH + ts) * BATCH * NHID + j] = hv; // output
            }
            // raw barrier: drain LDS only; global loads/stores stay in flight
            asm volatile("s_waitcnt lgkmcnt(0)" ::: "memory");
            __builtin_amdgcn_s_barrier();
            __builtin_amdgcn_sched_barrier(0);
        }

        // next chunk's DMA (and all h stores) must be complete before use
        asm volatile("s_waitcnt vmcnt(0)" ::: "memory");
        __builtin_amdgcn_s_barrier();
        __builtin_amdgcn_sched_barrier(0);
        cbuf ^= 1;
    }
}

// ---------------------------------------------------------------------------
// K3: logits = h_last @ Why + by
// ---------------------------------------------------------------------------
__global__ __launch_bounds__(256) void head_kernel(const float* __restrict__ hlast,
                                                   const float* __restrict__ Why,
                                                   const float* __restrict__ by,
                                                   float* __restrict__ out) {
    const int idx = blockIdx.x * 256 + threadIdx.x;
    if (idx >= BATCH * NOUT) return;
    const int b = idx / NOUT;
    const int o = idx % NOUT;
    const float* h = hlast + (size_t)b * NHID;
    float acc = by[o];
#pragma unroll 8
    for (int k = 0; k < NHID; ++k)
        acc = fmaf(h[k], Why[(size_t)k * NOUT + o], acc);
    out[idx] = acc;
}

// ---------------------------------------------------------------------------
extern "C" void kernel_launch(void* const* d_in, const int* in_sizes, int n_in,
                              void* d_out, int out_size, void* d_ws, size_t ws_size,
                              hipStream_t stream) {
    const float* x   = (const float*)d_in[0];
    const float* Wxh = (const float*)d_in[1];
    const float* Whh = (const float*)d_in[2];
    const float* Why = (const float*)d_in[3];
    const float* bh  = (const float*)d_in[4];
    const float* by  = (const float*)d_in[5];
    float* out  = (float*)d_out;
    float* hreg = out + BATCH * NOUT;   // h region starts after the 1280 logits

    proj_kernel<<<(SEQ * BATCH) / 32, 256, 0, stream>>>(x, Wxh, bh, hreg);
    scan_kernel<<<BATCH, 256, 0, stream>>>(Whh, hreg);
    head_kernel<<<5, 256, 0, stream>>>(hreg + (size_t)(SEQ - 1) * BATCH * NHID,
                                       Why, by, out);
}

// Round 5
// 1219.874 us; speedup vs baseline: 1.4354x; 1.0080x over previous
//
#include <hip/hip_runtime.h>
#include <math.h>

#define SEQ   2048
#define BATCH  128
#define NINP    64
#define NHID   128
#define NOUT    10
#define CH      64              // timesteps per LDS chunk
#define NCHUNK (SEQ / CH)

typedef const float __attribute__((address_space(1)))* gptr_t;
typedef float       __attribute__((address_space(3)))* lptr_t;

// ---------------------------------------------------------------------------
// K1: xW[s][b][j] = sum_i x[s][b][i]*Wxh[i][j] + bh[j]
// (unchanged from R3 — verified correct)
// ---------------------------------------------------------------------------
__global__ __launch_bounds__(256) void proj_kernel(const float* __restrict__ x,
                                                   const float* __restrict__ Wxh,
                                                   const float* __restrict__ bh,
                                                   float* __restrict__ xw) {
    __shared__ float Wlds[NINP * NHID];   // 32 KB
    __shared__ float xs[32 * NINP];       // 8 KB
    const int t = threadIdx.x;
    const size_t r0 = (size_t)blockIdx.x * 32;

#pragma unroll
    for (int i = 0; i < 8; ++i)
        ((float4*)Wlds)[t + 256 * i] = ((const float4*)Wxh)[t + 256 * i];
    const float4* xg = (const float4*)(x + r0 * NINP);
    ((float4*)xs)[t]       = xg[t];
    ((float4*)xs)[t + 256] = xg[t + 256];
    __syncthreads();

    const int tj = t & 31;
    const int tr = t >> 5;
    const int j  = 4 * tj;
    const float4 bhv = *(const float4*)(bh + j);
    float acc[4][4];
#pragma unroll
    for (int r = 0; r < 4; ++r) {
        acc[r][0] = bhv.x; acc[r][1] = bhv.y; acc[r][2] = bhv.z; acc[r][3] = bhv.w;
    }
#pragma unroll 8
    for (int i = 0; i < NINP; ++i) {
        const float4 w4 = *(const float4*)&Wlds[i * NHID + j];
#pragma unroll
        for (int r = 0; r < 4; ++r) {
            const float xv = xs[(4 * tr + r) * NINP + i];
            acc[r][0] = fmaf(xv, w4.x, acc[r][0]);
            acc[r][1] = fmaf(xv, w4.y, acc[r][1]);
            acc[r][2] = fmaf(xv, w4.z, acc[r][2]);
            acc[r][3] = fmaf(xv, w4.w, acc[r][3]);
        }
    }
#pragma unroll
    for (int r = 0; r < 4; ++r) {
        float4 o = { acc[r][0], acc[r][1], acc[r][2], acc[r][3] };
        *(float4*)(xw + (r0 + 4 * tr + r) * NHID + j) = o;
    }
}

// ---------------------------------------------------------------------------
// K2: scan. One block (4 waves) per batch row.
// Wave w owns k-slice AND output-slice [32w, 32w+32): its next-step h inputs
// are its own outputs -> h lives in a register (vh, lane i = h[32w+i]);
// broadcast via v_readlane (VALU pipe), NOT LDS. Only the 4 per-output
// partial sums cross waves, via double-buffered P[2][4][128] (1 barrier/step,
// raw s_barrier + lgkmcnt only -> chunk DMA + h stores stay in flight).
//   lane l: accumulates partials for outputs j=l and j=64+l over its wave's
//   32 k-rows: 32 readlane + 64 FMA, zero LDS in phase A.
// ---------------------------------------------------------------------------
__global__ __launch_bounds__(256) void scan_kernel(const float* __restrict__ Whh,
                                                   float* __restrict__ hbuf) {
    __shared__ float xwc[2][CH][NHID];   // 64 KB, double-buffered xw chunks
    __shared__ float P[2][4][NHID];      // 4 KB, double-buffered partials

    const int b  = blockIdx.x;
    const int t  = threadIdx.x;
    const int w  = t >> 6;        // wave 0..3
    const int l  = t & 63;
    const int jj = l & 31;        // output index within wave's slice
    const int j0 = 32 * w;

    // ---- Whh rows [32w,32w+32), columns l and l+64 -> 64 pinned VGPRs ----
    float wx[32], wy[32];
    {
        const float* wp = Whh + (size_t)j0 * NHID + l;
#pragma unroll
        for (int i = 0; i < 32; ++i) {
            wx[i] = wp[(size_t)i * NHID];
            wy[i] = wp[(size_t)i * NHID + 64];
        }
#pragma unroll
        for (int i = 0; i < 32; ++i) {
            asm volatile("" : "+v"(wx[i]));
            asm volatile("" : "+v"(wy[i]));
        }
    }

    float* rowbase = hbuf + (size_t)b * NHID;

    // ---- async chunk loader (R3-verified linear mapping) ----
    auto issue_chunk = [&](int c, int nb) {
#pragma unroll
        for (int i = 0; i < 8; ++i) {
            const int f  = (i * 4 + w) * 256 + l * 4;  // float offset in chunk
            const int tl = f >> 7;                     // local timestep
            const int jx = f & 127;                    // hidden index
            const float* gp = hbuf + ((size_t)(c * CH + tl) * BATCH + b) * NHID + jx;
            lptr_t lp = (lptr_t)&xwc[nb][0][0] + (i * 4 + w) * 256;  // wave-uniform
            __builtin_amdgcn_global_load_lds((gptr_t)gp, lp, 16, 0, 0);
        }
    };

    issue_chunk(0, 0);
    asm volatile("s_waitcnt vmcnt(0)" ::: "memory");
    __syncthreads();

    float vh = 0.f;   // lane i (i<32): h[32w+i]; lanes 32-63 replicated
    int cbuf = 0;

    for (int c = 0; c < NCHUNK; ++c) {
        if (c + 1 < NCHUNK) issue_chunk(c + 1, cbuf ^ 1);

#pragma unroll 2
        for (int ts = 0; ts < CH; ++ts) {
            const int pb = ts & 1;
            // xw prefetch (depends only on chunk DMA; overlaps phase A)
            const float xwv = xwc[cbuf][ts][j0 + jj];

            // ---- phase A: partials via readlane broadcast (no LDS) ----
            float ax = 0.f, ay = 0.f;
#pragma unroll
            for (int i = 0; i < 32; ++i) {
                const float hr = __uint_as_float(
                    __builtin_amdgcn_readlane(__float_as_uint(vh), i));
                ax = fmaf(hr, wx[i], ax);
                ay = fmaf(hr, wy[i], ay);
            }
            P[pb][w][l]      = ax;   // partial for output j=l
            P[pb][w][l + 64] = ay;   // partial for output j=64+l

            asm volatile("s_waitcnt lgkmcnt(0)" ::: "memory");
            __builtin_amdgcn_s_barrier();
            __builtin_amdgcn_sched_barrier(0);

            // ---- phase B: reduce 4 partials for own output j=j0+jj ----
            const float p0 = P[pb][0][j0 + jj];
            const float p1 = P[pb][1][j0 + jj];
            const float p2 = P[pb][2][j0 + jj];
            const float p3 = P[pb][3][j0 + jj];
            const float z  = ((p0 + p1) + (p2 + p3)) + xwv;

            // fast tanh: (e-1)/(e+1), e = 2^(2z*log2e), clamped
            const float zc = fminf(fmaxf(z, -15.f), 15.f);
            const float e  = __builtin_amdgcn_exp2f(zc * 2.8853900817779268f);
            const float hv = (e - 1.f) * __builtin_amdgcn_rcpf(e + 1.f);
            vh = hv;   // all 64 lanes replicated; lanes 0-31 feed readlane

            if (l < 32)   // coalesced 128 B per wave, fire-and-forget
                rowbase[(size_t)(c * CH + ts) * BATCH * NHID + j0 + l] = hv;
        }

        // next chunk's DMA (and h stores) must complete before buffer swap
        asm volatile("s_waitcnt vmcnt(0)" ::: "memory");
        __builtin_amdgcn_s_barrier();
        __builtin_amdgcn_sched_barrier(0);
        cbuf ^= 1;
    }
}

// ---------------------------------------------------------------------------
// K3: logits = h_last @ Why + by
// ---------------------------------------------------------------------------
__global__ __launch_bounds__(256) void head_kernel(const float* __restrict__ hlast,
                                                   const float* __restrict__ Why,
                                                   const float* __restrict__ by,
                                                   float* __restrict__ out) {
    const int idx = blockIdx.x * 256 + threadIdx.x;
    if (idx >= BATCH * NOUT) return;
    const int b = idx / NOUT;
    const int o = idx % NOUT;
    const float* h = hlast + (size_t)b * NHID;
    float acc = by[o];
#pragma unroll 8
    for (int k = 0; k < NHID; ++k)
        acc = fmaf(h[k], Why[(size_t)k * NOUT + o], acc);
    out[idx] = acc;
}

// ---------------------------------------------------------------------------
extern "C" void kernel_launch(void* const* d_in, const int* in_sizes, int n_in,
                              void* d_out, int out_size, void* d_ws, size_t ws_size,
                              hipStream_t stream) {
    const float* x   = (const float*)d_in[0];
    const float* Wxh = (const float*)d_in[1];
    const float* Whh = (const float*)d_in[2];
    const float* Why = (const float*)d_in[3];
    const float* bh  = (const float*)d_in[4];
    const float* by  = (const float*)d_in[5];
    float* out  = (float*)d_out;
    float* hreg = out + BATCH * NOUT;   // h region starts after the 1280 logits

    proj_kernel<<<(SEQ * BATCH) / 32, 256, 0, stream>>>(x, Wxh, bh, hreg);
    scan_kernel<<<BATCH, 256, 0, stream>>>(Whh, hreg);
    head_kernel<<<5, 256, 0, stream>>>(hreg + (size_t)(SEQ - 1) * BATCH * NHID,
                                       Why, by, out);
}